// Round 3
// baseline (643.385 us; speedup 1.0000x reference)
//
#include <hip/hip_runtime.h>

// Problem constants (fixed by reference setup_inputs)
#define B_ 4
#define N_ 32768       // points per batch
#define C_ 128         // channels
#define D_ 32          // cubic dim
#define V_ (D_ * D_ * D_)   // 32768 voxels
#define NBUCK 512           // per-batch buckets: (32/4)^3, 4^3-voxel cells
#define NBUCK_T (NBUCK * B_)  // 2048 total

// Native vector type: required by __builtin_nontemporal_{load,store}
typedef float f4 __attribute__((ext_vector_type(4)));

// ---------------------------------------------------------------------------
// Kernel 1: transpose (B, C, V) -> (B, V, C), fully vectorized (~30 us).
// ---------------------------------------------------------------------------
__global__ __launch_bounds__(256) void transpose_kernel(
    const float* __restrict__ in,   // (B, C, V)
    float* __restrict__ out)        // (B, V, C)
{
    __shared__ float lds[C_ * 33];
    const int b  = blockIdx.y;
    const int v0 = blockIdx.x * 32;
    const float* inb  = in  + (size_t)b * C_ * V_;
    float*       outb = out + (size_t)b * C_ * V_;
    const int t = threadIdx.x;

    const int vq = t & 7;     // float4 index along v
    const int ci = t >> 3;    // 0..31
#pragma unroll
    for (int r = 0; r < 4; ++r) {
        const int c = ci + r * 32;
        const f4 f = __builtin_nontemporal_load(
            reinterpret_cast<const f4*>(inb + (size_t)c * V_ + v0 + vq * 4));
        float* d = &lds[c * 33 + vq * 4];
        d[0] = f.x; d[1] = f.y; d[2] = f.z; d[3] = f.w;
    }

    __syncthreads();

    const int c4 = (t & 31) << 2;  // channel quad
    const int vr = t >> 5;         // 0..1 (+8r)
#pragma unroll
    for (int r = 0; r < 4; ++r) {
        const int v = vr + r * 8;
        f4 g;
        g.x = lds[(c4 + 0) * 33 + v];
        g.y = lds[(c4 + 1) * 33 + v];
        g.z = lds[(c4 + 2) * 33 + v];
        g.w = lds[(c4 + 3) * 33 + v];
        *reinterpret_cast<f4*>(outb + (size_t)(v0 + v) * C_ + c4) = g;
    }
}

// ---------------------------------------------------------------------------
// Counting sort of point indices by 4^3-voxel bucket, so the gather
// processes spatially-adjacent points back-to-back (L2-local table reads).
// ---------------------------------------------------------------------------
__device__ __forceinline__ int bucket_of(const float* __restrict__ pp) {
    const float s = (D_ - 1) * 0.5f;     // 15.5 -> lower coords in [0,31]
    const int lx = (int)floorf((pp[0] + 1.0f) * s);
    const int ly = (int)floorf((pp[1] + 1.0f) * s);
    const int lz = (int)floorf((pp[2] + 1.0f) * s);
    return ((lx >> 2) << 6) | ((ly >> 2) << 3) | (lz >> 2);  // 0..511
}

__global__ __launch_bounds__(256) void zero_hist_kernel(unsigned* __restrict__ hist) {
    hist[blockIdx.x * 256 + threadIdx.x] = 0u;   // grid = NBUCK_T/256 = 8
}

__global__ __launch_bounds__(256) void hist_kernel(
    const float* __restrict__ ptcloud, unsigned* __restrict__ hist)
{
    const int p = blockIdx.x * 256 + threadIdx.x;       // 512 blocks
    const int bg = ((p >> 15) << 9) | bucket_of(ptcloud + (size_t)p * 3);
    atomicAdd(&hist[bg], 1u);
}

// Exclusive prefix sum over NBUCK_T=2048 counters. One 256-thread block,
// 8 bins/thread; Hillis-Steele scan of the 256 per-thread sums in LDS.
__global__ __launch_bounds__(256) void scan_kernel(
    const unsigned* __restrict__ hist, unsigned* __restrict__ cursor)
{
    __shared__ unsigned ssum[256];
    const int t = threadIdx.x;
    unsigned v[8], s = 0;
#pragma unroll
    for (int i = 0; i < 8; ++i) { v[i] = hist[t * 8 + i]; s += v[i]; }
    ssum[t] = s;
    __syncthreads();
    for (int ofs = 1; ofs < 256; ofs <<= 1) {
        const unsigned x = (t >= ofs) ? ssum[t - ofs] : 0u;
        __syncthreads();
        ssum[t] += x;
        __syncthreads();
    }
    unsigned run = ssum[t] - s;   // exclusive prefix of this thread's chunk
#pragma unroll
    for (int i = 0; i < 8; ++i) { cursor[t * 8 + i] = run; run += v[i]; }
}

__global__ __launch_bounds__(256) void scatter_kernel(
    const float* __restrict__ ptcloud, unsigned* __restrict__ cursor,
    unsigned* __restrict__ order)
{
    const int p = blockIdx.x * 256 + threadIdx.x;       // 512 blocks
    const int bg = ((p >> 15) << 9) | bucket_of(ptcloud + (size_t)p * 3);
    const unsigned pos = atomicAdd(&cursor[bg], 1u);
    order[pos] = (unsigned)p;
}

// ---------------------------------------------------------------------------
// Kernel 2: gather, processing points in bucket-sorted order.
// One WAVE per point (4 points / 256-thread block). Lane l: corner parity
// kk = l>>5, channel quad c4 = (l&31)*4. 4 independent 1 KiB/wave loads in
// flight, then 4 nontemporal 1 KiB/wave stores (out is write-once; NT keeps
// featsT resident in L2/L3). Sorted order makes the loads L2-local.
// ---------------------------------------------------------------------------
__global__ __launch_bounds__(256) void gather_kernel(
    const float* __restrict__ ptcloud,   // (B, N, 3)
    const float* __restrict__ featsT,    // (B, V, C)
    const unsigned* __restrict__ order,  // (B*N) sorted point ids
    float* __restrict__ out)             // (B, N, 8, C)
{
    const int t = threadIdx.x;
    const int sp = (blockIdx.x << 2) + (t >> 6);   // sorted position
    const int point = (int)order[sp];              // wave-uniform
    const int l  = t & 63;
    const int kk = l >> 5;               // corner z-parity (0/1)
    const int c4 = (l & 31) << 2;        // channel quad base
    const int b  = point >> 15;          // N_ = 32768

    const float* pp = ptcloud + (size_t)point * 3;
    const float s = (D_ - 1) * 0.5f;     // 15.5
    const int lx = (int)floorf((pp[0] + 1.0f) * s);
    const int ly = (int)floorf((pp[1] + 1.0f) * s);
    const int lz = (int)floorf((pp[2] + 1.0f) * s);

    const int iz = lz + kk;
    const bool vz = (unsigned)iz < (unsigned)D_;
    const int cz = min(max(iz, 0), D_ - 1);

    const float* src = featsT + (size_t)b * V_ * C_ + c4;
    float* dst = out + ((size_t)point * 8 + kk) * C_ + c4;

    f4 v[4];
    float m[4];
#pragma unroll
    for (int j = 0; j < 4; ++j) {        // corner k = 2*j + kk
        const int ix = lx + (j >> 1);
        const int iy = ly + (j & 1);
        const bool valid = vz &
                           ((unsigned)ix < (unsigned)D_) &
                           ((unsigned)iy < (unsigned)D_);
        const int cx = min(max(ix, 0), D_ - 1);
        const int cy = min(max(iy, 0), D_ - 1);
        const int flat = (cx * D_ + cy) * D_ + cz;
        v[j] = *reinterpret_cast<const f4*>(src + (size_t)flat * C_);
        m[j] = valid ? 1.0f : 0.0f;
    }

#pragma unroll
    for (int j = 0; j < 4; ++j) {
        f4 r = v[j] * m[j];
        __builtin_nontemporal_store(
            r, reinterpret_cast<f4*>(dst + (size_t)(2 * j) * C_));
    }
}

// Unsorted variant (fallback when ws fits featsT but not the sort arrays).
__global__ __launch_bounds__(256) void gather_unsorted_kernel(
    const float* __restrict__ ptcloud,
    const float* __restrict__ featsT,
    float* __restrict__ out)
{
    const int t = threadIdx.x;
    const int point = (blockIdx.x << 2) + (t >> 6);
    const int l  = t & 63;
    const int kk = l >> 5;
    const int c4 = (l & 31) << 2;
    const int b  = point >> 15;

    const float* pp = ptcloud + (size_t)point * 3;
    const float s = (D_ - 1) * 0.5f;
    const int lx = (int)floorf((pp[0] + 1.0f) * s);
    const int ly = (int)floorf((pp[1] + 1.0f) * s);
    const int lz = (int)floorf((pp[2] + 1.0f) * s);

    const int iz = lz + kk;
    const bool vz = (unsigned)iz < (unsigned)D_;
    const int cz = min(max(iz, 0), D_ - 1);

    const float* src = featsT + (size_t)b * V_ * C_ + c4;
    float* dst = out + ((size_t)point * 8 + kk) * C_ + c4;

    f4 v[4];
    float m[4];
#pragma unroll
    for (int j = 0; j < 4; ++j) {
        const int ix = lx + (j >> 1);
        const int iy = ly + (j & 1);
        const bool valid = vz &
                           ((unsigned)ix < (unsigned)D_) &
                           ((unsigned)iy < (unsigned)D_);
        const int cx = min(max(ix, 0), D_ - 1);
        const int cy = min(max(iy, 0), D_ - 1);
        const int flat = (cx * D_ + cy) * D_ + cz;
        v[j] = *reinterpret_cast<const f4*>(src + (size_t)flat * C_);
        m[j] = valid ? 1.0f : 0.0f;
    }
#pragma unroll
    for (int j = 0; j < 4; ++j) {
        f4 r = v[j] * m[j];
        __builtin_nontemporal_store(
            r, reinterpret_cast<f4*>(dst + (size_t)(2 * j) * C_));
    }
}

// ---------------------------------------------------------------------------
// Fallback: direct gather from (B, C, V) if workspace is too small.
// ---------------------------------------------------------------------------
__global__ __launch_bounds__(128) void gather_direct_kernel(
    const float* __restrict__ ptcloud,
    const float* __restrict__ feats,     // (B, C, V)
    float* __restrict__ out)
{
    const int point = blockIdx.x;
    const int b = point >> 15;
    const int c = threadIdx.x;

    const float* pp = ptcloud + (size_t)point * 3;
    const float s = (D_ - 1) * 0.5f;
    const int lx = (int)floorf((pp[0] + 1.0f) * s);
    const int ly = (int)floorf((pp[1] + 1.0f) * s);
    const int lz = (int)floorf((pp[2] + 1.0f) * s);

    const float* fb = feats + ((size_t)b * C_ + c) * V_;
    float* ob = out + (size_t)point * 8 * C_ + c;

#pragma unroll
    for (int k = 0; k < 8; ++k) {
        const int ix = lx + (k >> 2);
        const int iy = ly + ((k >> 1) & 1);
        const int iz = lz + (k & 1);
        const bool valid = ((unsigned)ix < (unsigned)D_) &
                           ((unsigned)iy < (unsigned)D_) &
                           ((unsigned)iz < (unsigned)D_);
        const int cx = min(max(ix, 0), D_ - 1);
        const int cy = min(max(iy, 0), D_ - 1);
        const int cz = min(max(iz, 0), D_ - 1);
        const int flat = (cx * D_ + cy) * D_ + cz;
        ob[(size_t)k * C_] = fb[flat] * (valid ? 1.0f : 0.0f);
    }
}

extern "C" void kernel_launch(void* const* d_in, const int* in_sizes, int n_in,
                              void* d_out, int out_size, void* d_ws, size_t ws_size,
                              hipStream_t stream) {
    const float* ptcloud = (const float*)d_in[0];   // (B,N,3)
    const float* feats   = (const float*)d_in[1];   // (B,C,D,D,D)
    float* out = (float*)d_out;                     // (B,N,8,C)

    const size_t featsT_bytes = (size_t)B_ * C_ * V_ * sizeof(float);  // 64 MiB
    const size_t hist_bytes   = NBUCK_T * sizeof(unsigned);            // 8 KiB
    const size_t order_bytes  = (size_t)B_ * N_ * sizeof(unsigned);    // 512 KiB
    const size_t need_sort    = featsT_bytes + 2 * hist_bytes + order_bytes;

    if (ws_size >= need_sort) {
        char* w = (char*)d_ws;
        float*    featsT = (float*)w;                                  // 64 MiB
        unsigned* hist   = (unsigned*)(w + featsT_bytes);
        unsigned* cursor = (unsigned*)(w + featsT_bytes + hist_bytes);
        unsigned* order  = (unsigned*)(w + featsT_bytes + 2 * hist_bytes);

        dim3 tg(V_ / 32, B_);                       // (1024, 4)
        transpose_kernel<<<tg, 256, 0, stream>>>(feats, featsT);
        zero_hist_kernel<<<NBUCK_T / 256, 256, 0, stream>>>(hist);
        hist_kernel<<<(B_ * N_) / 256, 256, 0, stream>>>(ptcloud, hist);
        scan_kernel<<<1, 256, 0, stream>>>(hist, cursor);
        scatter_kernel<<<(B_ * N_) / 256, 256, 0, stream>>>(ptcloud, cursor, order);
        gather_kernel<<<(B_ * N_) / 4, 256, 0, stream>>>(ptcloud, featsT, order, out);
    } else if (ws_size >= featsT_bytes) {
        float* featsT = (float*)d_ws;
        dim3 tg(V_ / 32, B_);
        transpose_kernel<<<tg, 256, 0, stream>>>(feats, featsT);
        gather_unsorted_kernel<<<(B_ * N_) / 4, 256, 0, stream>>>(ptcloud, featsT, out);
    } else {
        gather_direct_kernel<<<B_ * N_, 128, 0, stream>>>(ptcloud, feats, out);
    }
}